// Round 1
// baseline (260.050 us; speedup 1.0000x reference)
//
#include <hip/hip_runtime.h>
#include <stdint.h>

#define IN_F   8192
#define OUT_F  8192
#define MB     64
#define RANK   16
#define KSPLIT 16

typedef _Float16 f16x8 __attribute__((ext_vector_type(8)));
typedef _Float16 f16x2 __attribute__((ext_vector_type(2)));
typedef float    f32x4 __attribute__((ext_vector_type(4)));

__device__ __forceinline__ unsigned pk2h(float a, float b) {
    return __builtin_bit_cast(unsigned, __builtin_amdgcn_cvt_pkrtz(a, b));
}

// Decode 8 nvfp4 codes (dword p) -> f16x8 scaled by s2 (packed f16 pair).
// v_perm hi-byte LUT + sign bit3<<4. Verified in prior session (R5-R8).
__device__ __forceinline__ f16x8 decode8(unsigned p, unsigned s2) {
    unsigned q  = p >> 4;
    unsigned me = __builtin_amdgcn_perm(0x46444240u, 0x3E3C3800u, p & 0x07070707u);
    unsigned mo = __builtin_amdgcn_perm(0x46444240u, 0x3E3C3800u, q & 0x07070707u);
    unsigned he = ((p & 0x08080808u) << 4) | me;
    unsigned ho = ((q & 0x08080808u) << 4) | mo;
    unsigned bu0 = __builtin_amdgcn_perm(ho, he, 0x040C000Cu);
    unsigned bu1 = __builtin_amdgcn_perm(ho, he, 0x050C010Cu);
    unsigned bu2 = __builtin_amdgcn_perm(ho, he, 0x060C020Cu);
    unsigned bu3 = __builtin_amdgcn_perm(ho, he, 0x070C030Cu);
    f16x2 sv = __builtin_bit_cast(f16x2, s2);
    f16x2 h0 = __builtin_bit_cast(f16x2, bu0) * sv;
    f16x2 h1 = __builtin_bit_cast(f16x2, bu1) * sv;
    f16x2 h2 = __builtin_bit_cast(f16x2, bu2) * sv;
    f16x2 h3 = __builtin_bit_cast(f16x2, bu3) * sv;
    f16x8 b;
    b[0]=h0[0]; b[1]=h0[1]; b[2]=h1[0]; b[3]=h1[1];
    b[4]=h2[0]; b[5]=h2[1]; b[6]=h3[0]; b[7]=h3[1];
    return b;
}

// ---------------------------------------------------------------------------
// repack: W (either int32-expanded [FMT1] or packed uint8 row-major [FMT0])
// -> W2 in MFMA-fragment order, packed uint8, as uint2 per (lane, kstep):
//   U = ((((ks*64 + by)*4 + w)*16 + s)*64 + lane)
//   W2u2[U] = { packed_dword(row0, e), packed_dword(row0+16, e) }
//   row0 = by*128 + w*32 + (lane&15), e = ks*64 + s*4 + (lane>>4)
// Format is self-detected per block (first 64 dwords all <=255 -> FMT1).
// Block 0 additionally zeroes t. Fully coalesced 8B stores; 64B-segment reads.
// ---------------------------------------------------------------------------
__global__ __launch_bounds__(256) void repack_kernel(
    const void* __restrict__ Wpv, unsigned* __restrict__ W2,
    float* __restrict__ t)
{
    const int tid = threadIdx.x;
    const unsigned U = blockIdx.x * 256 + tid;

    unsigned v = ((const unsigned*)Wpv)[tid & 63];
    const bool fmt1 = (__ballot(v > 255u) == 0ull);

    if (blockIdx.x == 0) {
        for (int i = tid; i < MB * RANK; i += 256) t[i] = 0.f;
    }

    const int lane = U & 63;
    const int s    = (U >> 6) & 15;
    const int w    = (U >> 10) & 3;
    const int by   = (U >> 12) & 63;
    const int ks   = (U >> 18) & 15;
    const int l15  = lane & 15, quad = lane >> 4;
    const int row0 = by * 128 + w * 32 + l15;
    const int e    = ks * 64 + s * 4 + quad;

    unsigned d0, d1;
    if (fmt1) {
        const uint4* in4 = (const uint4*)Wpv;   // one byte per dword source
        uint4 a = in4[(size_t)row0 * 1024 + e];
        uint4 b = in4[(size_t)(row0 + 16) * 1024 + e];
        d0 = (a.x & 0xFFu) | ((a.y & 0xFFu) << 8) | ((a.z & 0xFFu) << 16) | (a.w << 24);
        d1 = (b.x & 0xFFu) | ((b.y & 0xFFu) << 8) | ((b.z & 0xFFu) << 16) | (b.w << 24);
    } else {
        const unsigned* in1 = (const unsigned*)Wpv; // packed uint8 row-major
        d0 = in1[(size_t)row0 * 1024 + e];
        d1 = in1[(size_t)(row0 + 16) * 1024 + e];
    }
    uint2 o; o.x = d0; o.y = d1;
    ((uint2*)W2)[U] = o;
}

// ---------------------------------------------------------------------------
// prep: grid (64 m, 4 kq). x quarter -> MFMA-A-fragment layout; partial t.
// (unchanged from previous session; t zeroed by repack block 0)
// ---------------------------------------------------------------------------
__global__ __launch_bounds__(256) void prep_kernel(
    const float* __restrict__ x, const float* __restrict__ lora_A,
    uint2* __restrict__ xf2, float* __restrict__ t)
{
    const int m = blockIdx.x, kq = blockIdx.y;
    const int tid = threadIdx.x;
    const int mt = m >> 4, l15 = m & 15;
    float acc[RANK];
#pragma unroll
    for (int r = 0; r < RANK; ++r) acc[r] = 0.f;

    const float4* x4 = (const float4*)(x + (size_t)m * IN_F);
    const float4* A4 = (const float4*)lora_A;
#pragma unroll
    for (int it = 0; it < 2; ++it) {
        int j = kq * 512 + it * 256 + tid;
        float4 xv = x4[j];
        uint2 u;
        u.x = pk2h(xv.x, xv.y);
        u.y = pk2h(xv.z, xv.w);
        int kstep = j >> 3, quad = (j >> 1) & 3, h = j & 1;
        xf2[(size_t)(((kstep * 4 + mt) * 64 + quad * 16 + l15) * 2 + h)] = u;
#pragma unroll
        for (int r = 0; r < RANK; ++r) {
            float4 av = A4[(size_t)r * (IN_F / 4) + j];
            acc[r] += xv.x * av.x + xv.y * av.y + xv.z * av.z + xv.w * av.w;
        }
    }
#pragma unroll
    for (int r = 0; r < RANK; ++r)
#pragma unroll
        for (int off = 32; off > 0; off >>= 1)
            acc[r] += __shfl_down(acc[r], off);

    __shared__ float red[4][RANK];
    int lane = tid & 63, wid = tid >> 6;
    if (lane == 0) {
#pragma unroll
        for (int r = 0; r < RANK; ++r) red[wid][r] = acc[r];
    }
    __syncthreads();
    if (tid < RANK)
        atomicAdd(&t[m * RANK + tid],
                  red[0][tid] + red[1][tid] + red[2][tid] + red[3][tid]);
}

__device__ __forceinline__ float4 lora4(const float* __restrict__ t, int m,
                                        const float* __restrict__ lora_B, int n4) {
    const float4* t4 = (const float4*)(t + m * RANK);
    float4 ta = t4[0], tb = t4[1], tc = t4[2], td = t4[3];
    float4 o;
    float* op = (float*)&o;
#pragma unroll
    for (int j = 0; j < 4; ++j) {
        const float4* B4 = (const float4*)(lora_B + (size_t)(n4 + j) * RANK);
        float4 b0 = B4[0], b1 = B4[1], b2 = B4[2], b3 = B4[3];
        op[j] = ta.x * b0.x + ta.y * b0.y + ta.z * b0.z + ta.w * b0.w
              + tb.x * b1.x + tb.y * b1.y + tb.z * b1.z + tb.w * b1.w
              + tc.x * b2.x + tc.y * b2.y + tc.z * b2.z + tc.w * b2.w
              + td.x * b3.x + td.y * b3.y + td.z * b3.z + td.w * b3.w;
    }
    return o;
}

__global__ __launch_bounds__(256) void lora_kernel(
    const float* __restrict__ t, const float* __restrict__ lora_B,
    float* __restrict__ out)
{
    const int gid = blockIdx.x * 256 + threadIdx.x;
    ((float4*)out)[gid] = lora4(t, gid >> 11, lora_B, (gid & 2047) * 4);
}

__global__ __launch_bounds__(256) void finish_kernel(
    const float* __restrict__ partial, const float* __restrict__ t,
    const float* __restrict__ lora_B, float* __restrict__ out)
{
    const int gid = blockIdx.x * 256 + threadIdx.x;
    float4 p = {0.f, 0.f, 0.f, 0.f};
#pragma unroll
    for (int ksp = 0; ksp < KSPLIT; ++ksp) {
        float4 v = ((const float4*)partial)[(size_t)ksp * (MB * OUT_F / 4) + gid];
        p.x += v.x; p.y += v.y; p.z += v.z; p.w += v.w;
    }
    float4 l = lora4(t, gid >> 11, lora_B, (gid & 2047) * 4);
    p.x += l.x; p.y += l.y; p.z += l.z; p.w += l.w;
    ((float4*)out)[gid] = p;
}

// ---------------------------------------------------------------------------
// main3: LDS-free streaming GEMM+dequant.
// grid (KSPLIT, 64), block 256 = 4 waves; wave owns 32 n x 64 m x 512 k.
// Weight read as ONE coalesced dwordx2 per lane per kstep from fragment-order
// W2; x fragments read coalesced from L2-resident xf; scales preloaded into
// 32 packed-f16 VGPRs. No barriers; compiler pipelines the unrolled loop.
// ---------------------------------------------------------------------------
template<int ATOMIC>
__global__ __launch_bounds__(256, 4) void main3_kernel(
    const unsigned* __restrict__ W2,
    const float*    __restrict__ scales,
    const uint4*    __restrict__ xf4,
    float*          __restrict__ dst)
{
    const int tid = threadIdx.x;
    const int lane = tid & 63, w = tid >> 6;
    const int l15 = lane & 15, quad = lane >> 4, qh = quad >> 1;
    const int ks = blockIdx.x, by = blockIdx.y;
    const int n0 = by * 128 + w * 32;
    const int row = n0 + l15;

    // ---- scale preload: 32 packed-f16 dwords (this lane's qh parity) ----
    unsigned sreg[2][16];
#pragma unroll
    for (int nt = 0; nt < 2; ++nt) {
        const float4* sp = (const float4*)(scales + (size_t)(row + nt * 16) * (IN_F / 16)
                                           + ks * 32);
#pragma unroll
        for (int i = 0; i < 8; ++i) {
            float4 v = sp[i];
            float a = qh ? v.y : v.x, b = qh ? v.w : v.z;
            sreg[nt][2 * i]     = pk2h(a, a);
            sreg[nt][2 * i + 1] = pk2h(b, b);
        }
    }

    f32x4 acc[4][2];
#pragma unroll
    for (int mt = 0; mt < 4; ++mt)
#pragma unroll
        for (int nt = 0; nt < 2; ++nt)
            acc[mt][nt] = (f32x4){0.f, 0.f, 0.f, 0.f};

    const uint2* wp = (const uint2*)W2
                    + (((size_t)(ks * 64 + by) * 4 + w) * 16) * 64 + lane;
    const uint4* xp = xf4 + (size_t)ks * 4096 + lane;

#pragma unroll
    for (int s = 0; s < 16; ++s) {
        uint2 u = wp[s * 64];
        f16x8 afr[4];
#pragma unroll
        for (int mt = 0; mt < 4; ++mt)
            afr[mt] = __builtin_bit_cast(f16x8, xp[(s * 4 + mt) * 64]);
#pragma unroll
        for (int nt = 0; nt < 2; ++nt) {
            unsigned p = nt ? u.y : u.x;
            f16x8 b = decode8(p, sreg[nt][s]);
#pragma unroll
            for (int mt = 0; mt < 4; ++mt)
                acc[mt][nt] = __builtin_amdgcn_mfma_f32_16x16x32_f16(
                    afr[mt], b, acc[mt][nt], 0, 0, 0);
        }
    }

    // epilogue: C/D col(n)=l15, row(m)=quad*4+r (+16*mt)
    if (ATOMIC == 0) {
        float* pb = dst + (size_t)ks * (MB * OUT_F);
#pragma unroll
        for (int mt = 0; mt < 4; ++mt)
#pragma unroll
            for (int nt = 0; nt < 2; ++nt)
#pragma unroll
                for (int r = 0; r < 4; ++r)
                    pb[(size_t)(mt * 16 + quad * 4 + r) * OUT_F + n0 + nt * 16 + l15]
                        = acc[mt][nt][r];
    } else {
#pragma unroll
        for (int mt = 0; mt < 4; ++mt)
#pragma unroll
            for (int nt = 0; nt < 2; ++nt)
#pragma unroll
                for (int r = 0; r < 4; ++r)
                    atomicAdd(&dst[(size_t)(mt * 16 + quad * 4 + r) * OUT_F
                                   + n0 + nt * 16 + l15], acc[mt][nt][r]);
    }
}

extern "C" void kernel_launch(void* const* d_in, const int* in_sizes, int n_in,
                              void* d_out, int out_size, void* d_ws, size_t ws_size,
                              hipStream_t stream)
{
    (void)in_sizes; (void)n_in; (void)out_size;
    const float* x      = (const float*)d_in[0];
    const void*  Wp     = (const void*)d_in[1];
    const float* scales = (const float*)d_in[2];
    const float* lora_A = (const float*)d_in[3];
    const float* lora_B = (const float*)d_in[4];
    float* out = (float*)d_out;

    char* ws = (char*)d_ws;
    float* t       = (float*)(ws + 4096);        // 4 KiB
    uint2* xf      = (uint2*)(ws + 65536);       // 1 MiB fragment-layout fp16 x
    float* partial = (float*)(ws + (2u << 20));  // KSPLIT * 2 MiB = 32 MiB
    const bool full = ws_size >= ((size_t)67 << 20);
    unsigned* W2 = full ? (unsigned*)(ws + (34u << 20))   // after partial
                        : (unsigned*)(ws + (2u << 20));   // partial unused

    // W2 dwords = OUT_F * IN_F / 8 = 8.4M -> 4.19M uint2 -> 16384 blocks
    repack_kernel<<<(OUT_F * (IN_F / 8) / 2) / 256, 256, 0, stream>>>(Wp, W2, t);
    prep_kernel<<<dim3(64, 4), 256, 0, stream>>>(x, lora_A, xf, t);

    if (full) {
        main3_kernel<0><<<dim3(KSPLIT, 64), 256, 0, stream>>>(
            W2, scales, (const uint4*)xf, partial);
        finish_kernel<<<(MB * OUT_F / 4) / 256, 256, 0, stream>>>(
            partial, t, lora_B, out);
    } else {
        lora_kernel<<<(MB * OUT_F / 4) / 256, 256, 0, stream>>>(t, lora_B, out);
        main3_kernel<1><<<dim3(KSPLIT, 64), 256, 0, stream>>>(
            W2, scales, (const uint4*)xf, out);
    }
}

// Round 2
// 239.784 us; speedup vs baseline: 1.0845x; 1.0845x over previous
//
#include <hip/hip_runtime.h>
#include <stdint.h>

#define IN_F   8192
#define OUT_F  8192
#define MB     64
#define RANK   16
#define KSPLIT 16

typedef _Float16 f16x8 __attribute__((ext_vector_type(8)));
typedef _Float16 f16x2 __attribute__((ext_vector_type(2)));
typedef float    f32x4 __attribute__((ext_vector_type(4)));

__device__ __forceinline__ unsigned pk2h(float a, float b) {
    return __builtin_bit_cast(unsigned, __builtin_amdgcn_cvt_pkrtz(a, b));
}

// Decode 8 nvfp4 codes (dword p) -> f16x8 scaled by s2 (packed f16 pair).
// v_perm hi-byte LUT + sign bit3<<4. Verified in prior session.
__device__ __forceinline__ f16x8 decode8(unsigned p, unsigned s2) {
    unsigned q  = p >> 4;
    unsigned me = __builtin_amdgcn_perm(0x46444240u, 0x3E3C3800u, p & 0x07070707u);
    unsigned mo = __builtin_amdgcn_perm(0x46444240u, 0x3E3C3800u, q & 0x07070707u);
    unsigned he = ((p & 0x08080808u) << 4) | me;
    unsigned ho = ((q & 0x08080808u) << 4) | mo;
    unsigned bu0 = __builtin_amdgcn_perm(ho, he, 0x040C000Cu);
    unsigned bu1 = __builtin_amdgcn_perm(ho, he, 0x050C010Cu);
    unsigned bu2 = __builtin_amdgcn_perm(ho, he, 0x060C020Cu);
    unsigned bu3 = __builtin_amdgcn_perm(ho, he, 0x070C030Cu);
    f16x2 sv = __builtin_bit_cast(f16x2, s2);
    f16x2 h0 = __builtin_bit_cast(f16x2, bu0) * sv;
    f16x2 h1 = __builtin_bit_cast(f16x2, bu1) * sv;
    f16x2 h2 = __builtin_bit_cast(f16x2, bu2) * sv;
    f16x2 h3 = __builtin_bit_cast(f16x2, bu3) * sv;
    f16x8 b;
    b[0]=h0[0]; b[1]=h0[1]; b[2]=h1[0]; b[3]=h1[1];
    b[4]=h2[0]; b[5]=h2[1]; b[6]=h3[0]; b[7]=h3[1];
    return b;
}

// pack 4 source dwords (low byte each) -> 1 packed dword [b0(x),b0(y),b0(z),b0(w)]
__device__ __forceinline__ unsigned pack4(uint4 a) {
    unsigned t0 = __builtin_amdgcn_perm(a.y, a.x, 0x0C0C0400u); // [x.b0, y.b0, 0, 0]
    unsigned t1 = __builtin_amdgcn_perm(a.w, a.z, 0x0C0C0400u); // [z.b0, w.b0, 0, 0]
    return __builtin_amdgcn_perm(t1, t0, 0x05040100u);          // [x,y,z,w]
}

// ---------------------------------------------------------------------------
// prep: grid (64 m, 4 kq). x quarter -> MFMA-A-fragment layout; t partials
// written per-kq (no atomics, no zero-init dependency on poisoned ws).
// ---------------------------------------------------------------------------
__global__ __launch_bounds__(256) void prep_kernel(
    const float* __restrict__ x, const float* __restrict__ lora_A,
    uint2* __restrict__ xf2, float* __restrict__ tp)
{
    const int m = blockIdx.x, kq = blockIdx.y;
    const int tid = threadIdx.x;
    const int mt = m >> 4, l15 = m & 15;
    float acc[RANK];
#pragma unroll
    for (int r = 0; r < RANK; ++r) acc[r] = 0.f;

    const float4* x4 = (const float4*)(x + (size_t)m * IN_F);
    const float4* A4 = (const float4*)lora_A;
#pragma unroll
    for (int it = 0; it < 2; ++it) {
        int j = kq * 512 + it * 256 + tid;
        float4 xv = x4[j];
        uint2 u;
        u.x = pk2h(xv.x, xv.y);
        u.y = pk2h(xv.z, xv.w);
        int kstep = j >> 3, quad = (j >> 1) & 3, h = j & 1;
        xf2[(size_t)(((kstep * 4 + mt) * 64 + quad * 16 + l15) * 2 + h)] = u;
#pragma unroll
        for (int r = 0; r < RANK; ++r) {
            float4 av = A4[(size_t)r * (IN_F / 4) + j];
            acc[r] += xv.x * av.x + xv.y * av.y + xv.z * av.z + xv.w * av.w;
        }
    }
#pragma unroll
    for (int r = 0; r < RANK; ++r)
#pragma unroll
        for (int off = 32; off > 0; off >>= 1)
            acc[r] += __shfl_down(acc[r], off);

    __shared__ float red[4][RANK];
    int lane = tid & 63, wid = tid >> 6;
    if (lane == 0) {
#pragma unroll
        for (int r = 0; r < RANK; ++r) red[wid][r] = acc[r];
    }
    __syncthreads();
    if (tid < RANK)
        tp[((size_t)kq * MB + m) * RANK + tid] =
            red[0][tid] + red[1][tid] + red[2][tid] + red[3][tid];
}

__device__ __forceinline__ float4 lora4(const float* __restrict__ tp, int m,
                                        const float* __restrict__ lora_B, int n4) {
    float ta[RANK];
#pragma unroll
    for (int r = 0; r < RANK; ++r) ta[r] = 0.f;
#pragma unroll
    for (int kq = 0; kq < 4; ++kq) {
        const float4* t4 = (const float4*)(tp + ((size_t)kq * MB + m) * RANK);
#pragma unroll
        for (int i = 0; i < 4; ++i) {
            float4 v = t4[i];
            ta[4*i+0] += v.x; ta[4*i+1] += v.y; ta[4*i+2] += v.z; ta[4*i+3] += v.w;
        }
    }
    float4 o;
    float* op = (float*)&o;
#pragma unroll
    for (int j = 0; j < 4; ++j) {
        const float4* B4 = (const float4*)(lora_B + (size_t)(n4 + j) * RANK);
        float s = 0.f;
#pragma unroll
        for (int i = 0; i < 4; ++i) {
            float4 b = B4[i];
            s += ta[4*i+0]*b.x + ta[4*i+1]*b.y + ta[4*i+2]*b.z + ta[4*i+3]*b.w;
        }
        op[j] = s;
    }
    return o;
}

__global__ __launch_bounds__(256) void lora_kernel(
    const float* __restrict__ tp, const float* __restrict__ lora_B,
    float* __restrict__ out)
{
    const int gid = blockIdx.x * 256 + threadIdx.x;
    ((float4*)out)[gid] = lora4(tp, gid >> 11, lora_B, (gid & 2047) * 4);
}

__global__ __launch_bounds__(256) void finish_kernel(
    const float* __restrict__ partial, const float* __restrict__ tp,
    const float* __restrict__ lora_B, float* __restrict__ out)
{
    const int gid = blockIdx.x * 256 + threadIdx.x;
    float4 p = {0.f, 0.f, 0.f, 0.f};
#pragma unroll
    for (int ksp = 0; ksp < KSPLIT; ++ksp) {
        float4 v = ((const float4*)partial)[(size_t)ksp * (MB * OUT_F / 4) + gid];
        p.x += v.x; p.y += v.y; p.z += v.z; p.w += v.w;
    }
    float4 l = lora4(tp, gid >> 11, lora_B, (gid & 2047) * 4);
    p.x += l.x; p.y += l.y; p.z += l.z; p.w += l.w;
    ((float4*)out)[gid] = p;
}

// ---------------------------------------------------------------------------
// main4: fused repack + GEMM + dequant. grid (KSPLIT, 64), block 256 = 4 waves.
// Block: 128 n-rows x 64 m x 512 k. Weight read ONCE, coalesced, natural
// k-major order (lanes sweep consecutive 16B within a row; full-line reqs),
// packed in-register (v_perm), staged via 2x8KiB LDS double buffer with XOR
// swizzle e^(row&14) (<=2-way bank aliasing = free), ds_read_b32 fragment
// dwords. Format self-detected per block. Two barriers per 4-kstep chunk.
// ---------------------------------------------------------------------------
template<int ATOMIC>
__global__ __launch_bounds__(256, 3) void main4_kernel(
    const void*  __restrict__ Wpv,
    const float* __restrict__ scales,
    const uint4* __restrict__ xf4,
    float*       __restrict__ dst)
{
    __shared__ __align__(16) unsigned wbuf[2][2048];   // 2 x 8 KiB

    const int tid = threadIdx.x;
    const int lane = tid & 63, w = tid >> 6;
    const int l15 = lane & 15, quad = lane >> 4, qh = quad >> 1;
    const int ks = blockIdx.x, by = blockIdx.y;
    const int n0 = by * 128 + w * 32;
    const int row = n0 + l15;

    // format detect (wave-uniform, L2-broadcast)
    unsigned dv = ((const unsigned*)Wpv)[lane];
    const bool fmt1 = (__ballot(dv > 255u) == 0ull);

    // ---- scale preload: 32 packed-f16 dwords (this lane's qh parity) ----
    unsigned sreg[2][16];
#pragma unroll
    for (int nt = 0; nt < 2; ++nt) {
        const float4* sp = (const float4*)(scales + (size_t)(row + nt * 16) * (IN_F / 16)
                                           + ks * 32);
#pragma unroll
        for (int i = 0; i < 8; ++i) {
            float4 vv = sp[i];
            float a = qh ? vv.y : vv.x, b = qh ? vv.w : vv.z;
            sreg[nt][2 * i]     = pk2h(a, a);
            sreg[nt][2 * i + 1] = pk2h(b, b);
        }
    }

    f32x4 acc[4][2];
#pragma unroll
    for (int mt = 0; mt < 4; ++mt)
#pragma unroll
        for (int nt = 0; nt < 2; ++nt)
            acc[mt][nt] = (f32x4){0.f, 0.f, 0.f, 0.f};

    const uint4* xp  = xf4 + (size_t)ks * 4096 + lane;
    const uint4* Wp4 = (const uint4*)Wpv;

    uint4 rg[8];   // staged chunk (fmt1: 8 loads; fmt0: 2 loads)

    // chunk c covers packed-dword e_glob in [ks*64 + c*16, +16), 128 rows
#define LOADC(c)                                                              \
    do {                                                                      \
        if (fmt1) {                                                           \
            _Pragma("unroll") for (int i = 0; i < 8; ++i) {                   \
                int rl = (tid >> 4) + i * 16;                                 \
                rg[i] = Wp4[(size_t)(by * 128 + rl) * 1024                    \
                            + (ks * 64 + (c) * 16 + (tid & 15))];             \
            }                                                                 \
        } else {                                                              \
            _Pragma("unroll") for (int i = 0; i < 2; ++i) {                   \
                int rl = (tid >> 2) + i * 64;                                 \
                rg[i] = Wp4[(size_t)(by * 128 + rl) * 256                     \
                            + (ks * 16 + (c) * 4 + (tid & 3))];               \
            }                                                                 \
        }                                                                     \
    } while (0)

#define WRITEC(buf)                                                           \
    do {                                                                      \
        if (fmt1) {                                                           \
            int te = tid & 15;                                                \
            _Pragma("unroll") for (int i = 0; i < 8; ++i) {                   \
                int rl = (tid >> 4) + i * 16;                                 \
                wbuf[buf][rl * 16 + (te ^ (rl & 14))] = pack4(rg[i]);         \
            }                                                                 \
        } else {                                                              \
            _Pragma("unroll") for (int i = 0; i < 2; ++i) {                   \
                int rl = (tid >> 2) + i * 64;                                 \
                int eb = (tid & 3) * 4;                                       \
                wbuf[buf][rl * 16 + ((eb + 0) ^ (rl & 14))] = rg[i].x;        \
                wbuf[buf][rl * 16 + ((eb + 1) ^ (rl & 14))] = rg[i].y;        \
                wbuf[buf][rl * 16 + ((eb + 2) ^ (rl & 14))] = rg[i].z;        \
                wbuf[buf][rl * 16 + ((eb + 3) ^ (rl & 14))] = rg[i].w;        \
            }                                                                 \
        }                                                                     \
    } while (0)

    LOADC(0);
    WRITEC(0);
    __syncthreads();
    LOADC(1);

#pragma unroll
    for (int c = 0; c < 4; ++c) {
#pragma unroll
        for (int sc = 0; sc < 4; ++sc) {
            const int s = c * 4 + sc;
            f16x8 afr[4];
#pragma unroll
            for (int mt = 0; mt < 4; ++mt)
                afr[mt] = __builtin_bit_cast(f16x8, xp[(s * 4 + mt) * 64]);
#pragma unroll
            for (int nt = 0; nt < 2; ++nt) {
                const int rl = w * 32 + nt * 16 + l15;
                unsigned p = wbuf[c & 1][rl * 16 + ((sc * 4 + quad) ^ (l15 & 14))];
                f16x8 b = decode8(p, sreg[nt][s]);
#pragma unroll
                for (int mt = 0; mt < 4; ++mt)
                    acc[mt][nt] = __builtin_amdgcn_mfma_f32_16x16x32_f16(
                        afr[mt], b, acc[mt][nt], 0, 0, 0);
            }
        }
        if (c < 3) {
            __syncthreads();                 // all waves done reading buf[(c+1)&1]
            WRITEC((c + 1) & 1);
            if (c < 2) LOADC(c + 2);
            __syncthreads();                 // chunk c+1 visible
        }
    }
#undef LOADC
#undef WRITEC

    // epilogue: C/D col(n)=l15, row(m)=quad*4+r (+16*mt)
    if (ATOMIC == 0) {
        float* pb = dst + (size_t)ks * (MB * OUT_F);
#pragma unroll
        for (int mt = 0; mt < 4; ++mt)
#pragma unroll
            for (int nt = 0; nt < 2; ++nt)
#pragma unroll
                for (int r = 0; r < 4; ++r)
                    pb[(size_t)(mt * 16 + quad * 4 + r) * OUT_F + n0 + nt * 16 + l15]
                        = acc[mt][nt][r];
    } else {
#pragma unroll
        for (int mt = 0; mt < 4; ++mt)
#pragma unroll
            for (int nt = 0; nt < 2; ++nt)
#pragma unroll
                for (int r = 0; r < 4; ++r)
                    atomicAdd(&dst[(size_t)(mt * 16 + quad * 4 + r) * OUT_F
                                   + n0 + nt * 16 + l15], acc[mt][nt][r]);
    }
}

extern "C" void kernel_launch(void* const* d_in, const int* in_sizes, int n_in,
                              void* d_out, int out_size, void* d_ws, size_t ws_size,
                              hipStream_t stream)
{
    (void)in_sizes; (void)n_in; (void)out_size;
    const float* x      = (const float*)d_in[0];
    const void*  Wp     = (const void*)d_in[1];
    const float* scales = (const float*)d_in[2];
    const float* lora_A = (const float*)d_in[3];
    const float* lora_B = (const float*)d_in[4];
    float* out = (float*)d_out;

    char* ws = (char*)d_ws;
    float* tp      = (float*)ws;                 // 16 KiB (4 kq x 64 m x 16 r)
    uint2* xf      = (uint2*)(ws + 65536);       // 1 MiB fragment-layout fp16 x
    float* partial = (float*)(ws + (2u << 20));  // KSPLIT * 2 MiB = 32 MiB
    const bool full = ws_size >= ((size_t)34 << 20);

    prep_kernel<<<dim3(64, 4), 256, 0, stream>>>(x, lora_A, xf, tp);

    if (full) {
        main4_kernel<0><<<dim3(KSPLIT, 64), 256, 0, stream>>>(
            Wp, scales, (const uint4*)xf, partial);
        finish_kernel<<<(MB * OUT_F / 4) / 256, 256, 0, stream>>>(
            partial, tp, lora_B, out);
    } else {
        lora_kernel<<<(MB * OUT_F / 4) / 256, 256, 0, stream>>>(tp, lora_B, out);
        main4_kernel<1><<<dim3(KSPLIT, 64), 256, 0, stream>>>(
            Wp, scales, (const uint4*)xf, out);
    }
}

// Round 4
// 235.271 us; speedup vs baseline: 1.1053x; 1.0192x over previous
//
#include <hip/hip_runtime.h>
#include <stdint.h>

#define IN_F   8192
#define OUT_F  8192
#define MB     64
#define RANK   16
#define KSPLIT 16

typedef _Float16 f16x8 __attribute__((ext_vector_type(8)));
typedef _Float16 f16x2 __attribute__((ext_vector_type(2)));
typedef float    f32x4 __attribute__((ext_vector_type(4)));

__device__ __forceinline__ unsigned pk2h(float a, float b) {
    return __builtin_bit_cast(unsigned, __builtin_amdgcn_cvt_pkrtz(a, b));
}

#define MEMBAR() __asm__ __volatile__("" ::: "memory")

// Decode 8 nvfp4 codes (dword p) -> f16x8 scaled by s2 (packed f16 pair).
// v_perm hi-byte LUT + sign bit3<<4. Verified across prior rounds.
__device__ __forceinline__ f16x8 decode8(unsigned p, unsigned s2) {
    unsigned q  = p >> 4;
    unsigned me = __builtin_amdgcn_perm(0x46444240u, 0x3E3C3800u, p & 0x07070707u);
    unsigned mo = __builtin_amdgcn_perm(0x46444240u, 0x3E3C3800u, q & 0x07070707u);
    unsigned he = ((p & 0x08080808u) << 4) | me;
    unsigned ho = ((q & 0x08080808u) << 4) | mo;
    unsigned bu0 = __builtin_amdgcn_perm(ho, he, 0x040C000Cu);
    unsigned bu1 = __builtin_amdgcn_perm(ho, he, 0x050C010Cu);
    unsigned bu2 = __builtin_amdgcn_perm(ho, he, 0x060C020Cu);
    unsigned bu3 = __builtin_amdgcn_perm(ho, he, 0x070C030Cu);
    f16x2 sv = __builtin_bit_cast(f16x2, s2);
    f16x2 h0 = __builtin_bit_cast(f16x2, bu0) * sv;
    f16x2 h1 = __builtin_bit_cast(f16x2, bu1) * sv;
    f16x2 h2 = __builtin_bit_cast(f16x2, bu2) * sv;
    f16x2 h3 = __builtin_bit_cast(f16x2, bu3) * sv;
    f16x8 b;
    b[0]=h0[0]; b[1]=h0[1]; b[2]=h1[0]; b[3]=h1[1];
    b[4]=h2[0]; b[5]=h2[1]; b[6]=h3[0]; b[7]=h3[1];
    return b;
}

// pack 4 source dwords (low byte each) -> 1 packed dword [b0(x),b0(y),b0(z),b0(w)]
__device__ __forceinline__ unsigned pack4(uint4 a) {
    unsigned t0 = __builtin_amdgcn_perm(a.y, a.x, 0x0C0C0400u);
    unsigned t1 = __builtin_amdgcn_perm(a.w, a.z, 0x0C0C0400u);
    return __builtin_amdgcn_perm(t1, t0, 0x05040100u);
}

// ---------------------------------------------------------------------------
// prep: grid (64 m, 4 kq). x quarter -> MFMA-A-fragment layout; t partials
// written per-kq (no atomics, no zero-init dependency on poisoned ws).
// ---------------------------------------------------------------------------
__global__ __launch_bounds__(256) void prep_kernel(
    const float* __restrict__ x, const float* __restrict__ lora_A,
    uint2* __restrict__ xf2, float* __restrict__ tp)
{
    const int m = blockIdx.x, kq = blockIdx.y;
    const int tid = threadIdx.x;
    const int mt = m >> 4, l15 = m & 15;
    float acc[RANK];
#pragma unroll
    for (int r = 0; r < RANK; ++r) acc[r] = 0.f;

    const float4* x4 = (const float4*)(x + (size_t)m * IN_F);
    const float4* A4 = (const float4*)lora_A;
#pragma unroll
    for (int it = 0; it < 2; ++it) {
        int j = kq * 512 + it * 256 + tid;
        float4 xv = x4[j];
        uint2 u;
        u.x = pk2h(xv.x, xv.y);
        u.y = pk2h(xv.z, xv.w);
        int kstep = j >> 3, quad = (j >> 1) & 3, h = j & 1;
        xf2[(size_t)(((kstep * 4 + mt) * 64 + quad * 16 + l15) * 2 + h)] = u;
#pragma unroll
        for (int r = 0; r < RANK; ++r) {
            float4 av = A4[(size_t)r * (IN_F / 4) + j];
            acc[r] += xv.x * av.x + xv.y * av.y + xv.z * av.z + xv.w * av.w;
        }
    }
#pragma unroll
    for (int r = 0; r < RANK; ++r)
#pragma unroll
        for (int off = 32; off > 0; off >>= 1)
            acc[r] += __shfl_down(acc[r], off);

    __shared__ float red[4][RANK];
    int lane = tid & 63, wid = tid >> 6;
    if (lane == 0) {
#pragma unroll
        for (int r = 0; r < RANK; ++r) red[wid][r] = acc[r];
    }
    __syncthreads();
    if (tid < RANK)
        tp[((size_t)kq * MB + m) * RANK + tid] =
            red[0][tid] + red[1][tid] + red[2][tid] + red[3][tid];
}

__device__ __forceinline__ float4 lora4(const float* __restrict__ tp, int m,
                                        const float* __restrict__ lora_B, int n4) {
    float ta[RANK];
#pragma unroll
    for (int r = 0; r < RANK; ++r) ta[r] = 0.f;
#pragma unroll
    for (int kq = 0; kq < 4; ++kq) {
        const float4* t4 = (const float4*)(tp + ((size_t)kq * MB + m) * RANK);
#pragma unroll
        for (int i = 0; i < 4; ++i) {
            float4 v = t4[i];
            ta[4*i+0] += v.x; ta[4*i+1] += v.y; ta[4*i+2] += v.z; ta[4*i+3] += v.w;
        }
    }
    float4 o;
    float* op = (float*)&o;
#pragma unroll
    for (int j = 0; j < 4; ++j) {
        const float4* B4 = (const float4*)(lora_B + (size_t)(n4 + j) * RANK);
        float s = 0.f;
#pragma unroll
        for (int i = 0; i < 4; ++i) {
            float4 b = B4[i];
            s += ta[4*i+0]*b.x + ta[4*i+1]*b.y + ta[4*i+2]*b.z + ta[4*i+3]*b.w;
        }
        op[j] = s;
    }
    return o;
}

__global__ __launch_bounds__(256) void lora_kernel(
    const float* __restrict__ tp, const float* __restrict__ lora_B,
    float* __restrict__ out)
{
    const int gid = blockIdx.x * 256 + threadIdx.x;
    ((float4*)out)[gid] = lora4(tp, gid >> 11, lora_B, (gid & 2047) * 4);
}

__global__ __launch_bounds__(256) void finish_kernel(
    const float* __restrict__ partial, const float* __restrict__ tp,
    const float* __restrict__ lora_B, float* __restrict__ out)
{
    const int gid = blockIdx.x * 256 + threadIdx.x;
    float4 p = {0.f, 0.f, 0.f, 0.f};
#pragma unroll
    for (int ksp = 0; ksp < KSPLIT; ++ksp) {
        float4 v = ((const float4*)partial)[(size_t)ksp * (MB * OUT_F / 4) + gid];
        p.x += v.x; p.y += v.y; p.z += v.z; p.w += v.w;
    }
    float4 l = lora4(tp, gid >> 11, lora_B, (gid & 2047) * 4);
    p.x += l.x; p.y += l.y; p.z += l.z; p.w += l.w;
    ((float4*)out)[gid] = p;
}

// ---------------------------------------------------------------------------
// main5: fused repack + GEMM + dequant, no global loads in the MFMA loop
// except the coalesced W stream.
// grid (KSPLIT, 64), block 256 = 4 waves; wave owns 32 n x 64 m x 512 k.
// - x fragments staged once to LDS (64 KiB), single barrier, then barrier-free.
// - W loaded coalesced k-major (256B per 16 lanes), packed in-register,
//   written to a WAVE-PRIVATE 2 KiB LDS tile (swizzled so the consumer reads
//   one ds_read_b128 per nt per 4-kstep chunk). Writer == consumer wave ->
//   no block barriers in the k-loop.
// - depth-2 prefetch: rg[2][8] register double buffer, counted vmcnt(8)
//   (vmcnt FIFO stays pure-W: no x loads to couple with).
// LDS 64+16=80 KiB -> 2 blocks/CU, 8 waves/CU; grid 1024 = 2 clean rounds.
// ---------------------------------------------------------------------------
template<int ATOMIC>
__global__ __launch_bounds__(256, 2) void main5_kernel(
    const void*  __restrict__ Wpv,
    const float* __restrict__ scales,
    const uint4* __restrict__ xf4,
    float*       __restrict__ dst)
{
    __shared__ __align__(16) uint4    xs[4096];         // 64 KiB x fragments
    __shared__ __align__(16) unsigned wpk[4][2][512];   // 16 KiB packed W

    const int tid = threadIdx.x;
    const int lane = tid & 63, w = tid >> 6;
    const int l15 = lane & 15, quad = lane >> 4, qh = quad >> 1;
    const int ks = blockIdx.x, by = blockIdx.y;
    const int n0 = by * 128 + w * 32;
    const int row = n0 + l15;

    // format detect (wave-uniform, L2-broadcast)
    unsigned dv = ((const unsigned*)Wpv)[lane];
    const bool fmt1 = (__ballot(dv > 255u) == 0ull);

    // ---- scale preload: 32 packed-f16 dwords (this lane's qh parity) ----
    unsigned sreg[2][16];
#pragma unroll
    for (int nt = 0; nt < 2; ++nt) {
        const float4* sp = (const float4*)(scales + (size_t)(row + nt * 16) * (IN_F / 16)
                                           + ks * 32);
#pragma unroll
        for (int i = 0; i < 8; ++i) {
            float4 vv = sp[i];
            float a = qh ? vv.y : vv.x, b = qh ? vv.w : vv.z;
            sreg[nt][2 * i]     = pk2h(a, a);
            sreg[nt][2 * i + 1] = pk2h(b, b);
        }
    }

    const uint4* Wp4 = (const uint4*)Wpv;
    uint4 rg[2][8];

    // LOADW: chunk c (16 packed dwords x 32 wave rows) into rg[p]
#define LOADW(c, p)                                                           \
    do {                                                                      \
        if (fmt1) {                                                           \
            _Pragma("unroll") for (int i = 0; i < 8; ++i) {                   \
                int idx = i * 64 + lane;                                      \
                int r = idx >> 4, col = idx & 15;                             \
                rg[p][i] = Wp4[(size_t)(n0 + r) * 1024                        \
                               + (ks * 64 + (c) * 16 + col)];                 \
            }                                                                 \
        } else {                                                              \
            _Pragma("unroll") for (int i = 0; i < 2; ++i) {                   \
                int idx = i * 64 + lane;                                      \
                int r = idx >> 2, u = idx & 3;                                \
                rg[p][i] = Wp4[(size_t)(n0 + r) * 256                         \
                               + (ks * 16 + (c) * 4 + u)];                    \
            }                                                                 \
        }                                                                     \
    } while (0)

    // WRITEW: pack rg[p] into wave-private tile, swizzled [r][quad][s]
#define WRITEW(c, p)                                                          \
    do {                                                                      \
        unsigned* wb = &wpk[w][(c) & 1][0];                                   \
        if (fmt1) {                                                           \
            _Pragma("unroll") for (int i = 0; i < 8; ++i) {                   \
                int idx = i * 64 + lane;                                      \
                int r = idx >> 4, dcol = idx & 15;                            \
                wb[r * 16 + (dcol & 3) * 4 + (dcol >> 2)] = pack4(rg[p][i]);  \
            }                                                                 \
        } else {                                                              \
            _Pragma("unroll") for (int i = 0; i < 2; ++i) {                   \
                int idx = i * 64 + lane;                                      \
                int r = idx >> 2, u = idx & 3;                                \
                wb[r * 16 + 0 * 4 + u] = rg[p][i].x;                          \
                wb[r * 16 + 1 * 4 + u] = rg[p][i].y;                          \
                wb[r * 16 + 2 * 4 + u] = rg[p][i].z;                          \
                wb[r * 16 + 3 * 4 + u] = rg[p][i].w;                          \
            }                                                                 \
        }                                                                     \
    } while (0)

    // ---- prologue: xs loads first, then W(0), W(1); stores overlap W flight
    uint4 xr[16];
    {
        const uint4* gsrc = xf4 + (size_t)ks * 4096;
#pragma unroll
        for (int i = 0; i < 16; ++i) xr[i] = gsrc[i * 256 + tid];
    }
    LOADW(0, 0);
    LOADW(1, 1);
#pragma unroll
    for (int i = 0; i < 16; ++i) xs[i * 256 + tid] = xr[i];   // waits xs only
    __syncthreads();

    f32x4 acc[4][2];
#pragma unroll
    for (int mt = 0; mt < 4; ++mt)
#pragma unroll
        for (int nt = 0; nt < 2; ++nt)
            acc[mt][nt] = (f32x4){0.f, 0.f, 0.f, 0.f};

    MEMBAR();
    __builtin_amdgcn_s_waitcnt(0x0F78);   // vmcnt(8): rg[0] landed, rg[1] flying
    MEMBAR();
    WRITEW(0, 0);

#pragma unroll
    for (int c = 0; c < 4; ++c) {
        // ---- compute chunk c from wave-private tile ----
        const uint4* wb4 = (const uint4*)&wpk[w][c & 1][0];
        uint4 b0 = wb4[(0 * 16 + l15) * 4 + quad];
        uint4 b1 = wb4[(1 * 16 + l15) * 4 + quad];
#pragma unroll
        for (int sc = 0; sc < 4; ++sc) {
            const int s = c * 4 + sc;
            f16x8 afr[4];
#pragma unroll
            for (int mt = 0; mt < 4; ++mt)
                afr[mt] = __builtin_bit_cast(f16x8, xs[(s * 4 + mt) * 64 + lane]);
            const unsigned pw0 = sc == 0 ? b0.x : sc == 1 ? b0.y : sc == 2 ? b0.z : b0.w;
            const unsigned pw1 = sc == 0 ? b1.x : sc == 1 ? b1.y : sc == 2 ? b1.z : b1.w;
            f16x8 bb0 = decode8(pw0, sreg[0][s]);
#pragma unroll
            for (int mt = 0; mt < 4; ++mt)
                acc[mt][0] = __builtin_amdgcn_mfma_f32_16x16x32_f16(
                    afr[mt], bb0, acc[mt][0], 0, 0, 0);
            f16x8 bb1 = decode8(pw1, sreg[1][s]);
#pragma unroll
            for (int mt = 0; mt < 4; ++mt)
                acc[mt][1] = __builtin_amdgcn_mfma_f32_16x16x32_f16(
                    afr[mt], bb1, acc[mt][1], 0, 0, 0);
        }
        // ---- stage chunk c+1; keep depth-2 prefetch in flight ----
        if (c < 3) {
            MEMBAR();
            if (c < 2) LOADW(c + 2, c & 1);
            MEMBAR();
            if (c < 2) { __builtin_amdgcn_s_waitcnt(0x0F78); }   // vmcnt(8)
            else       { __builtin_amdgcn_s_waitcnt(0x0F70); }   // vmcnt(0)
            MEMBAR();
            WRITEW(c + 1, (c + 1) & 1);
        }
    }
#undef LOADW
#undef WRITEW

    // epilogue: C/D col(n)=l15, row(m)=quad*4+r (+16*mt)
    if (ATOMIC == 0) {
        float* pb = dst + (size_t)ks * (MB * OUT_F);
#pragma unroll
        for (int mt = 0; mt < 4; ++mt)
#pragma unroll
            for (int nt = 0; nt < 2; ++nt)
#pragma unroll
                for (int r = 0; r < 4; ++r)
                    pb[(size_t)(mt * 16 + quad * 4 + r) * OUT_F + n0 + nt * 16 + l15]
                        = acc[mt][nt][r];
    } else {
#pragma unroll
        for (int mt = 0; mt < 4; ++mt)
#pragma unroll
            for (int nt = 0; nt < 2; ++nt)
#pragma unroll
                for (int r = 0; r < 4; ++r)
                    atomicAdd(&dst[(size_t)(mt * 16 + quad * 4 + r) * OUT_F
                                   + n0 + nt * 16 + l15], acc[mt][nt][r]);
    }
}

extern "C" void kernel_launch(void* const* d_in, const int* in_sizes, int n_in,
                              void* d_out, int out_size, void* d_ws, size_t ws_size,
                              hipStream_t stream)
{
    (void)in_sizes; (void)n_in; (void)out_size;
    const float* x      = (const float*)d_in[0];
    const void*  Wp     = (const void*)d_in[1];
    const float* scales = (const float*)d_in[2];
    const float* lora_A = (const float*)d_in[3];
    const float* lora_B = (const float*)d_in[4];
    float* out = (float*)d_out;

    char* ws = (char*)d_ws;
    float* tp      = (float*)ws;                 // 16 KiB (4 kq x 64 m x 16 r)
    uint2* xf      = (uint2*)(ws + 65536);       // 1 MiB fragment-layout fp16 x
    float* partial = (float*)(ws + (2u << 20));  // KSPLIT * 2 MiB = 32 MiB
    const bool full = ws_size >= ((size_t)34 << 20);

    prep_kernel<<<dim3(64, 4), 256, 0, stream>>>(x, lora_A, xf, tp);

    if (full) {
        main5_kernel<0><<<dim3(KSPLIT, 64), 256, 0, stream>>>(
            Wp, scales, (const uint4*)xf, partial);
        finish_kernel<<<(MB * OUT_F / 4) / 256, 256, 0, stream>>>(
            partial, tp, lora_B, out);
    } else {
        lora_kernel<<<(MB * OUT_F / 4) / 256, 256, 0, stream>>>(tp, lora_B, out);
        main5_kernel<1><<<dim3(KSPLIT, 64), 256, 0, stream>>>(
            Wp, scales, (const uint4*)xf, out);
    }
}